// Round 7
// baseline (1016.575 us; speedup 1.0000x reference)
//
#include <hip/hip_runtime.h>
#include <hip/hip_cooperative_groups.h>

namespace cg = cooperative_groups;

// PointConv v5: ONE cooperative kernel, 5 phases separated by grid.sync():
//  P0 init:      head = -1, stats = 0
//  P1 build_cvt: ref_feat fp32->bf16 table (RNE) + per-query linked list
//  P2 accum:     16 lanes/query chase list (barrier-free, grid-stride),
//                bf16 gather, fp32 accumulate -> accF/possum (global)
//  P3 gemm:      (accF@Wm^T + posdiff@Wp^T + cnt*b)/max(cnt,1) -> out,
//                fused per-channel sum/sumsq atomics -> stats
//  P4 bnapply:   inline BN-prep + normalize + ReLU in-place
// LDS = 26.6 KB -> 6 blocks/CU (accum phase keeps ~96 chains/CU in flight).
// Fallback: v3-style multi-kernel path if cooperative launch unavailable.

__device__ __forceinline__ float bf_lo(unsigned u) {
  union { unsigned u; float f; } c; c.u = u << 16; return c.f;
}
__device__ __forceinline__ float bf_hi(unsigned u) {
  union { unsigned u; float f; } c; c.u = u & 0xFFFF0000u; return c.f;
}
__device__ __forceinline__ unsigned pack_bf(float x, float y) {
  union { float f; unsigned u; } a, b; a.f = x; b.f = y;
  unsigned lo = (a.u + 0x7FFFu + ((a.u >> 16) & 1u)) >> 16;
  unsigned hi = (b.u + 0x7FFFu + ((b.u >> 16) & 1u)) >> 16;
  return lo | (hi << 16);
}

struct P {
  const int* eq; const int* er;
  int* head; int2* node;
  const float4* featf; uint4* featb;
  const float* bxyz; const float* qxyz;
  const float* Wm; const float* Wp; const float* bm; const float* bp;
  const float* gamma; const float* beta;
  float* out; float* stats; float4* accF4; float* possum;
  int M, E, n8; float inv_m;
};

__global__ __launch_bounds__(256, 6) void k_all(P p) {
  cg::grid_group grid = cg::this_grid();
  __shared__ float sA[32 * 132];   // 16896 B: acc tile / stats-red
  __shared__ float sW[128 * 18];   // 9216 B: W k16-tile (float2 stride 9) / sc+sh
  __shared__ float sPS[32][4];     // 512 B: per-row {sx,sy,sz,cnt}
  int t = threadIdx.x;
  int nb = gridDim.x;
  int gtid = blockIdx.x * 256 + t;
  int gsz = nb * 256;

  // ---- P0: init ----
  for (int i = gtid; i < p.M; i += gsz) p.head[i] = -1;
  if (gtid < 256) p.stats[gtid] = 0.f;
  grid.sync();

  // ---- P1: cvt + build ----
  for (int i = gtid; i < p.n8; i += gsz) {
    float4 a = p.featf[2 * i], b = p.featf[2 * i + 1];
    uint4 o;
    o.x = pack_bf(a.x, a.y);
    o.y = pack_bf(a.z, a.w);
    o.z = pack_bf(b.x, b.y);
    o.w = pack_bf(b.z, b.w);
    p.featb[i] = o;
  }
  for (int i = gtid; i < p.E; i += gsz) {
    int q = p.eq[i];
    int prev = atomicExch(&p.head[q], i);
    p.node[i] = make_int2(prev, p.er[i]);
  }
  __threadfence();
  grid.sync();

  // ---- P2: accum (16 lanes/query, barrier-free) ----
  {
    int grp = gtid >> 4, l = gtid & 15, ngrp = gsz >> 4;
    for (int q = grp; q < p.M; q += ngrp) {
      int i = p.head[q];
      float a0=0.f,a1=0.f,a2=0.f,a3=0.f,a4=0.f,a5=0.f,a6=0.f,a7=0.f;
      float ps = 0.f, c = 0.f;
      while (i >= 0) {
        int2 nd = p.node[i];            // {next, ref}
        int r = nd.y;
        uint4 v = p.featb[(size_t)r * 16 + l];
        a0 += bf_lo(v.x); a1 += bf_hi(v.x);
        a2 += bf_lo(v.y); a3 += bf_hi(v.y);
        a4 += bf_lo(v.z); a5 += bf_hi(v.z);
        a6 += bf_lo(v.w); a7 += bf_hi(v.w);
        if (l < 3) ps += p.bxyz[r * 4 + 1 + l];
        c += 1.f;
        i = nd.x;
      }
      p.accF4[(size_t)q * 32 + 2 * l]     = make_float4(a0, a1, a2, a3);
      p.accF4[(size_t)q * 32 + 2 * l + 1] = make_float4(a4, a5, a6, a7);
      if (l < 3) p.possum[q * 4 + l] = ps;
      if (l == 3) p.possum[q * 4 + 3] = c;
    }
  }
  __threadfence();
  grid.sync();

  // ---- P3: gemm + stats ----
  {
    const float* accF = (const float*)p.accF4;
    const float4* possum4 = (const float4*)p.possum;
    int ntile = (p.M + 31) / 32;
    int q0l = (t >> 5) << 2;  // row base 0,4,...,28
    int cb = t & 31;          // channel base; channels = cb + 32j
    float2* sW2 = (float2*)sW;                 // row stride 9 float2
    const float2* Wm2 = (const float2*)p.Wm;   // row stride 64 float2
    for (int tile = blockIdx.x; tile < ntile; tile += nb) {
      int q0 = tile * 32;
      #pragma unroll
      for (int i = 0; i < 4; ++i) {     // stage accF tile
        int f = t + 256 * i;
        int q = f >> 5;
        int kk = (f & 31) << 2;
        float4 v = make_float4(0.f, 0.f, 0.f, 0.f);
        if (q0 + q < p.M) v = *(const float4*)&accF[(size_t)(q0 + q) * 128 + kk];
        *(float4*)&sA[q * 132 + kk] = v;
      }
      if (t < 32) {
        float4 ps = make_float4(0.f, 0.f, 0.f, 0.f);
        if (q0 + t < p.M) ps = possum4[q0 + t];
        sPS[t][0] = ps.x; sPS[t][1] = ps.y; sPS[t][2] = ps.z; sPS[t][3] = ps.w;
      }
      float acc[4][4];
      #pragma unroll
      for (int i = 0; i < 4; ++i)
        #pragma unroll
        for (int j = 0; j < 4; ++j) acc[i][j] = 0.f;
      for (int kt = 0; kt < 8; ++kt) {
        __syncthreads();   // kt=0: sA/sPS ready; kt>0: sW reads done
        #pragma unroll
        for (int i = 0; i < 4; ++i) {   // stage W[:, kt*16 .. kt*16+15]
          int f = t + 256 * i;          // 1024 float2 slots
          int c = f >> 3;
          int kk2 = f & 7;
          sW2[c * 9 + kk2] = Wm2[c * 64 + kt * 8 + kk2];
        }
        __syncthreads();
        #pragma unroll
        for (int kk4 = 0; kk4 < 4; ++kk4) {
          float4 av[4];
          float2 wa[4], wb[4];
          #pragma unroll
          for (int i = 0; i < 4; ++i)
            av[i] = *(const float4*)&sA[(q0l + i) * 132 + kt * 16 + (kk4 << 2)];
          #pragma unroll
          for (int j = 0; j < 4; ++j) {
            int c = cb + 32 * j;
            wa[j] = sW2[c * 9 + kk4 * 2];
            wb[j] = sW2[c * 9 + kk4 * 2 + 1];
          }
          #pragma unroll
          for (int i = 0; i < 4; ++i)
            #pragma unroll
            for (int j = 0; j < 4; ++j) {
              acc[i][j] = fmaf(av[i].x, wa[j].x, acc[i][j]);
              acc[i][j] = fmaf(av[i].y, wa[j].y, acc[i][j]);
              acc[i][j] = fmaf(av[i].z, wb[j].x, acc[i][j]);
              acc[i][j] = fmaf(av[i].w, wb[j].y, acc[i][j]);
            }
        }
      }
      float fcnt[4], inv[4], dx[4], dy[4], dz[4];
      #pragma unroll
      for (int i = 0; i < 4; ++i) {
        int row = q0l + i;
        int q = q0 + row;
        if (q < p.M) {
          float fc = sPS[row][3];
          fcnt[i] = fc;
          inv[i] = 1.f / fmaxf(fc, 1.f);
          dx[i] = sPS[row][0] - fc * p.qxyz[q * 4 + 1];
          dy[i] = sPS[row][1] - fc * p.qxyz[q * 4 + 2];
          dz[i] = sPS[row][2] - fc * p.qxyz[q * 4 + 3];
        } else {
          fcnt[i] = 0.f; inv[i] = 1.f; dx[i] = dy[i] = dz[i] = 0.f;
        }
      }
      float psum[4], psq[4];
      #pragma unroll
      for (int j = 0; j < 4; ++j) {
        int c = cb + 32 * j;
        float w0 = p.Wp[c * 3 + 0], w1 = p.Wp[c * 3 + 1], w2 = p.Wp[c * 3 + 2];
        float bb = p.bm[c] + p.bp[c];
        float s = 0.f, s2 = 0.f;
        #pragma unroll
        for (int i = 0; i < 4; ++i) {
          int q = q0 + q0l + i;
          float v = acc[i][j] + dx[i] * w0 + dy[i] * w1 + dz[i] * w2 + fcnt[i] * bb;
          float val = v * inv[i];
          if (q >= p.M) val = 0.f;     // padded rows contribute zero
          if (q < p.M) p.out[(size_t)q * 128 + c] = val;
          s += val; s2 += val * val;
        }
        psum[j] = s; psq[j] = s2;
      }
      __syncthreads();                 // all sA reads done -> reuse as red
      float* red = sA;                 // [0..1023]=sum, [1024..2047]=sumsq
      int rg = t >> 5;
      #pragma unroll
      for (int j = 0; j < 4; ++j) {
        int c = cb + 32 * j;
        red[c * 8 + rg] = psum[j];
        red[1024 + c * 8 + rg] = psq[j];
      }
      __syncthreads();
      if (t < 128) {
        float s = 0.f, s2 = 0.f;
        #pragma unroll
        for (int r = 0; r < 8; ++r) {
          s += red[t * 8 + r];
          s2 += red[1024 + t * 8 + r];
        }
        atomicAdd(&p.stats[t], s);
        atomicAdd(&p.stats[128 + t], s2);
      }
      __syncthreads();                 // red reads done before next tile
    }
  }
  __threadfence();
  grid.sync();

  // ---- P4: bnapply ----
  {
    float* sc = sW;            // reuse sW space
    float* sh = sW + 128;
    if (t < 128) {
      float mu = p.stats[t] * p.inv_m;
      float var = p.stats[128 + t] * p.inv_m - mu * mu;
      var = fmaxf(var, 0.f);
      float s = p.gamma[t] * rsqrtf(var + 1e-5f);
      sc[t] = s;
      sh[t] = p.beta[t] - mu * s;
    }
    __syncthreads();
    const float4* sc4 = (const float4*)sc;
    const float4* sh4 = (const float4*)sh;
    float4* o4 = (float4*)p.out;
    int total4 = p.M * 32;
    for (int i = gtid; i < total4; i += gsz) {
      float4 v = o4[i];
      float4 s = sc4[i & 31];
      float4 h = sh4[i & 31];
      v.x = fmaxf(fmaf(v.x, s.x, h.x), 0.f);
      v.y = fmaxf(fmaf(v.y, s.y, h.y), 0.f);
      v.z = fmaxf(fmaf(v.z, s.z, h.z), 0.f);
      v.w = fmaxf(fmaf(v.w, s.w, h.w), 0.f);
      o4[i] = v;
    }
  }
}

// ================= fallback path (v3-proven kernels) =================

__global__ __launch_bounds__(256) void k_build_cvt(
    const int* __restrict__ eq, const int* __restrict__ er,
    int* __restrict__ head, int2* __restrict__ node,
    const float4* __restrict__ featf, uint4* __restrict__ featb,
    float* __restrict__ stats, int E_, int n8) {
  int i = blockIdx.x * blockDim.x + threadIdx.x;
  if (i < 256) stats[i] = 0.f;
  if (i < n8) {
    float4 a = featf[2 * i], b = featf[2 * i + 1];
    uint4 o;
    o.x = pack_bf(a.x, a.y);
    o.y = pack_bf(a.z, a.w);
    o.z = pack_bf(b.x, b.y);
    o.w = pack_bf(b.z, b.w);
    featb[i] = o;
  }
  if (i < E_) {
    int q = eq[i];
    int prev = atomicExch(&head[q], i);
    node[i] = make_int2(prev, er[i]);
  }
}

__global__ __launch_bounds__(256) void k_accum_b(const int* __restrict__ head,
                                                 const int2* __restrict__ node,
                                                 const uint4* __restrict__ featb,
                                                 const float* __restrict__ bxyz,
                                                 float4* __restrict__ accF4,
                                                 float* __restrict__ possum, int M_) {
  int q = blockIdx.x * 16 + (threadIdx.x >> 4);
  int l = threadIdx.x & 15;
  if (q >= M_) return;
  int i = head[q];
  float a0=0.f,a1=0.f,a2=0.f,a3=0.f,a4=0.f,a5=0.f,a6=0.f,a7=0.f;
  float ps = 0.f, c = 0.f;
  while (i >= 0) {
    int2 nd = node[i];
    int r = nd.y;
    uint4 v = featb[(size_t)r * 16 + l];
    a0 += bf_lo(v.x); a1 += bf_hi(v.x);
    a2 += bf_lo(v.y); a3 += bf_hi(v.y);
    a4 += bf_lo(v.z); a5 += bf_hi(v.z);
    a6 += bf_lo(v.w); a7 += bf_hi(v.w);
    if (l < 3) ps += bxyz[r * 4 + 1 + l];
    c += 1.f;
    i = nd.x;
  }
  accF4[(size_t)q * 32 + 2 * l]     = make_float4(a0, a1, a2, a3);
  accF4[(size_t)q * 32 + 2 * l + 1] = make_float4(a4, a5, a6, a7);
  if (l < 3) possum[q * 4 + l] = ps;
  if (l == 3) possum[q * 4 + 3] = c;
}

__global__ __launch_bounds__(256) void k_gemm(
    const float* __restrict__ accF, const float4* __restrict__ possum4,
    const float* __restrict__ qxyz,
    const float* __restrict__ Wm, const float* __restrict__ Wp,
    const float* __restrict__ bm, const float* __restrict__ bp,
    float* __restrict__ out, float* __restrict__ stats, int M_) {
  __shared__ float sA[32 * 132];
  __shared__ float sW[128 * 34];
  int t = threadIdx.x;
  int q0 = blockIdx.x * 32;
  #pragma unroll
  for (int i = 0; i < 4; ++i) {
    int f = t + 256 * i;
    int q = f >> 5;
    int kk = (f & 31) << 2;
    float4 v = make_float4(0.f, 0.f, 0.f, 0.f);
    if (q0 + q < M_) v = *(const float4*)&accF[(q0 + q) * 128 + kk];
    *(float4*)&sA[q * 132 + kk] = v;
  }
  float acc[4][4];
  #pragma unroll
  for (int i = 0; i < 4; ++i)
    #pragma unroll
    for (int j = 0; j < 4; ++j) acc[i][j] = 0.f;
  int q0l = (t >> 5) << 2;
  int cb = t & 31;
  float2* sW2 = (float2*)sW;
  const float2* Wm2 = (const float2*)Wm;
  for (int kt = 0; kt < 4; ++kt) {
    __syncthreads();
    #pragma unroll
    for (int i = 0; i < 8; ++i) {
      int f = t + 256 * i;
      int c = f >> 4;
      int kk2 = f & 15;
      sW2[c * 17 + kk2] = Wm2[c * 64 + kt * 16 + kk2];
    }
    __syncthreads();
    #pragma unroll
    for (int kk4 = 0; kk4 < 8; ++kk4) {
      float4 av[4];
      float2 wa[4], wb[4];
      #pragma unroll
      for (int i = 0; i < 4; ++i)
        av[i] = *(const float4*)&sA[(q0l + i) * 132 + kt * 32 + (kk4 << 2)];
      #pragma unroll
      for (int j = 0; j < 4; ++j) {
        int c = cb + 32 * j;
        wa[j] = sW2[c * 17 + kk4 * 2];
        wb[j] = sW2[c * 17 + kk4 * 2 + 1];
      }
      #pragma unroll
      for (int i = 0; i < 4; ++i)
        #pragma unroll
        for (int j = 0; j < 4; ++j) {
          acc[i][j] = fmaf(av[i].x, wa[j].x, acc[i][j]);
          acc[i][j] = fmaf(av[i].y, wa[j].y, acc[i][j]);
          acc[i][j] = fmaf(av[i].z, wb[j].x, acc[i][j]);
          acc[i][j] = fmaf(av[i].w, wb[j].y, acc[i][j]);
        }
    }
  }
  float fcnt[4], inv[4], dx[4], dy[4], dz[4];
  #pragma unroll
  for (int i = 0; i < 4; ++i) {
    int q = q0 + q0l + i;
    if (q < M_) {
      float4 ps = possum4[q];
      float fc = ps.w;
      fcnt[i] = fc;
      inv[i] = 1.f / fmaxf(fc, 1.f);
      dx[i] = ps.x - fc * qxyz[q * 4 + 1];
      dy[i] = ps.y - fc * qxyz[q * 4 + 2];
      dz[i] = ps.z - fc * qxyz[q * 4 + 3];
    } else {
      fcnt[i] = 0.f; inv[i] = 1.f; dx[i] = dy[i] = dz[i] = 0.f;
    }
  }
  float psum[4], psq[4];
  #pragma unroll
  for (int j = 0; j < 4; ++j) {
    int c = cb + 32 * j;
    float w0 = Wp[c * 3 + 0], w1 = Wp[c * 3 + 1], w2 = Wp[c * 3 + 2];
    float bb = bm[c] + bp[c];
    float s = 0.f, s2 = 0.f;
    #pragma unroll
    for (int i = 0; i < 4; ++i) {
      int q = q0 + q0l + i;
      float v = acc[i][j] + dx[i] * w0 + dy[i] * w1 + dz[i] * w2 + fcnt[i] * bb;
      float val = v * inv[i];
      if (q >= M_) val = 0.f;
      if (q < M_) out[q * 128 + c] = val;
      s += val; s2 += val * val;
    }
    psum[j] = s; psq[j] = s2;
  }
  __syncthreads();
  float* red = sA;
  int rg = t >> 5;
  #pragma unroll
  for (int j = 0; j < 4; ++j) {
    int c = cb + 32 * j;
    red[c * 8 + rg] = psum[j];
    red[1024 + c * 8 + rg] = psq[j];
  }
  __syncthreads();
  if (t < 128) {
    float s = 0.f, s2 = 0.f;
    #pragma unroll
    for (int r = 0; r < 8; ++r) {
      s += red[t * 8 + r];
      s2 += red[1024 + t * 8 + r];
    }
    atomicAdd(&stats[t], s);
    atomicAdd(&stats[128 + t], s2);
  }
}

__global__ __launch_bounds__(256) void k_bnapply(float* __restrict__ out,
                                                 const float* __restrict__ stats,
                                                 const float* __restrict__ gamma,
                                                 const float* __restrict__ beta,
                                                 float inv_m, int total4) {
  __shared__ float sc[128], sh[128];
  int t = threadIdx.x;
  if (t < 128) {
    float mu = stats[t] * inv_m;
    float var = stats[128 + t] * inv_m - mu * mu;
    var = fmaxf(var, 0.f);
    float s = gamma[t] * rsqrtf(var + 1e-5f);
    sc[t] = s;
    sh[t] = beta[t] - mu * s;
  }
  __syncthreads();
  const float4* sc4 = (const float4*)sc;
  const float4* sh4 = (const float4*)sh;
  float4* o4 = (float4*)out;
  for (int i = blockIdx.x * blockDim.x + t; i < total4;
       i += gridDim.x * blockDim.x) {
    float4 v = o4[i];
    float4 s = sc4[i & 31];
    float4 h = sh4[i & 31];
    v.x = fmaxf(fmaf(v.x, s.x, h.x), 0.f);
    v.y = fmaxf(fmaf(v.y, s.y, h.y), 0.f);
    v.z = fmaxf(fmaf(v.z, s.z, h.z), 0.f);
    v.w = fmaxf(fmaf(v.w, s.w, h.w), 0.f);
    o4[i] = v;
  }
}

static inline size_t align256(size_t x) { return (x + 255) & ~(size_t)255; }

extern "C" void kernel_launch(void* const* d_in, const int* in_sizes, int n_in,
                              void* d_out, int out_size, void* d_ws, size_t ws_size,
                              hipStream_t stream) {
  const float* ref_bxyz   = (const float*)d_in[0];
  const float* ref_feat   = (const float*)d_in[1];
  const float* query_bxyz = (const float*)d_in[2];
  const int*   e_ref      = (const int*)d_in[3];
  const int*   e_query    = (const int*)d_in[4];
  const float* W_pos      = (const float*)d_in[5];
  const float* b_pos      = (const float*)d_in[6];
  const float* W_mlp      = (const float*)d_in[7];
  const float* b_mlp      = (const float*)d_in[8];
  const float* gamma      = (const float*)d_in[9];
  const float* beta       = (const float*)d_in[10];

  int N_ = in_sizes[0] / 4;
  int M_ = in_sizes[2] / 4;
  int E_ = in_sizes[3];

  char* ws = (char*)d_ws;
  size_t off = 0;
  int*   head   = (int*)(ws + off);   off += align256((size_t)M_ * 4);
  int2*  node   = (int2*)(ws + off);  off += align256((size_t)E_ * 8);
  float* stats  = (float*)(ws + off); off += align256(2 * 128 * 4);
  float* possum = (float*)(ws + off); off += align256((size_t)M_ * 4 * 4);
  float* accF   = (float*)(ws + off); off += align256((size_t)M_ * 128 * 4);
  uint4* featb  = (uint4*)(ws + off);

  float* out = (float*)d_out;
  int n8 = N_ * 16;                 // uint4 groups (8 floats each)

  P p;
  p.eq = e_query; p.er = e_ref; p.head = head; p.node = node;
  p.featf = (const float4*)ref_feat; p.featb = featb;
  p.bxyz = ref_bxyz; p.qxyz = query_bxyz;
  p.Wm = W_mlp; p.Wp = W_pos; p.bm = b_mlp; p.bp = b_pos;
  p.gamma = gamma; p.beta = beta;
  p.out = out; p.stats = stats; p.accF4 = (float4*)accF; p.possum = possum;
  p.M = M_; p.E = E_; p.n8 = n8; p.inv_m = 1.f / (float)M_;

  int numCU = 256, maxb = 0;
  hipDeviceGetAttribute(&numCU, hipDeviceAttributeMultiprocessorCount, 0);
  hipError_t oe = hipOccupancyMaxActiveBlocksPerMultiprocessor(&maxb, k_all, 256, 0);
  if (oe != hipSuccess || maxb < 1) maxb = 4;
  int grid = numCU * maxb;

  void* args[] = { (void*)&p };
  hipError_t err = hipLaunchCooperativeKernel((void*)k_all, dim3(grid), dim3(256),
                                              args, 0, stream);
  if (err != hipSuccess) {
    // fallback: proven v3-style sequence
    int nwork = (E_ > n8) ? E_ : n8;
    hipMemsetAsync(head, 0xFF, (size_t)M_ * 4, stream);
    k_build_cvt<<<(nwork + 255) / 256, 256, 0, stream>>>(
        e_query, e_ref, head, node, (const float4*)ref_feat, featb, stats, E_, n8);
    k_accum_b<<<(M_ + 15) / 16, 256, 0, stream>>>(head, node, featb, ref_bxyz,
                                                  (float4*)accF, possum, M_);
    k_gemm<<<(M_ + 31) / 32, 256, 0, stream>>>(accF, (const float4*)possum,
                                               query_bxyz, W_mlp, W_pos, b_mlp,
                                               b_pos, out, stats, M_);
    k_bnapply<<<1024, 256, 0, stream>>>(out, stats, gamma, beta, 1.f / (float)M_,
                                        M_ * 32);
  }
}

// Round 8
// 350.721 us; speedup vs baseline: 2.8985x; 2.8985x over previous
//
#include <hip/hip_runtime.h>

// PointConv v6 (5 dispatches):
//  0. memset: head4 = -1  (M*4 sharded heads)
//  1. build_cvt: ref_feat fp32->bf16 table (RNE) + 4-way-sharded per-query
//                linked lists (atomicExch, shard = edge&3: 8-way contention
//                instead of 32-way) + zero stats
//  2. accum:  16 lanes/query chase the query's 4 chains sequentially;
//             uint4 gather = 8 bf16/lane, fp32 accumulate -> accF/possum
//  3. gemm:   (accF@Wm^T + posdiff@Wp^T + cnt*b)/max(cnt,1) -> out,
//             fused per-channel sum/sumsq atomics -> stats
//  4. bnapply: inline BN-prep + normalize + ReLU in-place
// Lesson r6/r7: no intra-kernel coupling of gather with anything barriered;
// phase separation via stream order only.

__device__ __forceinline__ float bf_lo(unsigned u) {
  union { unsigned u; float f; } c; c.u = u << 16; return c.f;
}
__device__ __forceinline__ float bf_hi(unsigned u) {
  union { unsigned u; float f; } c; c.u = u & 0xFFFF0000u; return c.f;
}
__device__ __forceinline__ unsigned pack_bf(float x, float y) {
  union { float f; unsigned u; } a, b; a.f = x; b.f = y;
  unsigned lo = (a.u + 0x7FFFu + ((a.u >> 16) & 1u)) >> 16;
  unsigned hi = (b.u + 0x7FFFu + ((b.u >> 16) & 1u)) >> 16;
  return lo | (hi << 16);
}

__global__ __launch_bounds__(256) void k_build_cvt(
    const int* __restrict__ eq, const int* __restrict__ er,
    int* __restrict__ head4, int2* __restrict__ node,
    const float4* __restrict__ featf, uint4* __restrict__ featb,
    float* __restrict__ stats, int E_, int n8) {
  int i = blockIdx.x * blockDim.x + threadIdx.x;
  if (i < 256) stats[i] = 0.f;          // zeroed for k_gemm's atomics
  if (i < n8) {
    float4 a = featf[2 * i], b = featf[2 * i + 1];
    uint4 o;
    o.x = pack_bf(a.x, a.y);
    o.y = pack_bf(a.z, a.w);
    o.z = pack_bf(b.x, b.y);
    o.w = pack_bf(b.z, b.w);
    featb[i] = o;
  }
  if (i < E_) {
    int q = eq[i];
    int prev = atomicExch(&head4[4 * q + (i & 3)], i);
    node[i] = make_int2(prev, er[i]);
  }
}

// 16 lanes per query; lane l owns channels 8l..8l+7 (one uint4 = 8 bf16).
// Chases the query's 4 sharded chains back-to-back.
__global__ __launch_bounds__(256) void k_accum_b(const int* __restrict__ head4,
                                                 const int2* __restrict__ node,
                                                 const uint4* __restrict__ featb,
                                                 const float* __restrict__ bxyz,
                                                 float4* __restrict__ accF4,
                                                 float* __restrict__ possum, int M_) {
  int q = blockIdx.x * 16 + (threadIdx.x >> 4);
  int l = threadIdx.x & 15;
  if (q >= M_) return;
  float a0=0.f,a1=0.f,a2=0.f,a3=0.f,a4=0.f,a5=0.f,a6=0.f,a7=0.f;
  float ps = 0.f, c = 0.f;
  #pragma unroll
  for (int s = 0; s < 4; ++s) {
    int i = head4[4 * q + s];
    while (i >= 0) {
      int2 nd = node[i];              // {next, ref}
      int r = nd.y;
      uint4 v = featb[(size_t)r * 16 + l];
      a0 += bf_lo(v.x); a1 += bf_hi(v.x);
      a2 += bf_lo(v.y); a3 += bf_hi(v.y);
      a4 += bf_lo(v.z); a5 += bf_hi(v.z);
      a6 += bf_lo(v.w); a7 += bf_hi(v.w);
      if (l < 3) ps += bxyz[r * 4 + 1 + l];
      c += 1.f;
      i = nd.x;
    }
  }
  accF4[(size_t)q * 32 + 2 * l]     = make_float4(a0, a1, a2, a3);
  accF4[(size_t)q * 32 + 2 * l + 1] = make_float4(a4, a5, a6, a7);
  if (l < 3) possum[q * 4 + l] = ps;
  if (l == 3) possum[q * 4 + 3] = c;
}

// 32 queries x 128 channels per block; 4x4 register microtile per thread.
// sW float2 stride 17 (bank-conflict-free per m136); fused stats epilogue.
__global__ __launch_bounds__(256) void k_gemm(
    const float* __restrict__ accF, const float4* __restrict__ possum4,
    const float* __restrict__ qxyz,
    const float* __restrict__ Wm, const float* __restrict__ Wp,
    const float* __restrict__ bm, const float* __restrict__ bp,
    float* __restrict__ out, float* __restrict__ stats, int M_) {
  __shared__ float sA[32 * 132];   // accF tile [32][128], stride 132
  __shared__ float sW[128 * 34];   // W k-tile [128][32] as float2 stride 17
  int t = threadIdx.x;
  int q0 = blockIdx.x * 32;
  #pragma unroll
  for (int i = 0; i < 4; ++i) {
    int f = t + 256 * i;
    int q = f >> 5;
    int kk = (f & 31) << 2;
    float4 v = make_float4(0.f, 0.f, 0.f, 0.f);
    if (q0 + q < M_) v = *(const float4*)&accF[(q0 + q) * 128 + kk];
    *(float4*)&sA[q * 132 + kk] = v;
  }
  float acc[4][4];
  #pragma unroll
  for (int i = 0; i < 4; ++i)
    #pragma unroll
    for (int j = 0; j < 4; ++j) acc[i][j] = 0.f;
  int q0l = (t >> 5) << 2;  // row base 0,4,...,28
  int cb = t & 31;          // channel base; thread's channels = cb + 32j
  float2* sW2 = (float2*)sW;                    // row stride 17 float2
  const float2* Wm2 = (const float2*)Wm;        // row stride 64 float2
  for (int kt = 0; kt < 4; ++kt) {
    __syncthreads();
    #pragma unroll
    for (int i = 0; i < 8; ++i) {   // stage W[:, kt*32 .. kt*32+31]
      int f = t + 256 * i;          // 2048 float2 slots
      int c = f >> 4;
      int kk2 = f & 15;
      sW2[c * 17 + kk2] = Wm2[c * 64 + kt * 16 + kk2];
    }
    __syncthreads();
    #pragma unroll
    for (int kk4 = 0; kk4 < 8; ++kk4) {
      float4 av[4];
      float2 wa[4], wb[4];
      #pragma unroll
      for (int i = 0; i < 4; ++i)
        av[i] = *(const float4*)&sA[(q0l + i) * 132 + kt * 32 + (kk4 << 2)];
      #pragma unroll
      for (int j = 0; j < 4; ++j) {
        int c = cb + 32 * j;
        wa[j] = sW2[c * 17 + kk4 * 2];
        wb[j] = sW2[c * 17 + kk4 * 2 + 1];
      }
      #pragma unroll
      for (int i = 0; i < 4; ++i)
        #pragma unroll
        for (int j = 0; j < 4; ++j) {
          acc[i][j] = fmaf(av[i].x, wa[j].x, acc[i][j]);
          acc[i][j] = fmaf(av[i].y, wa[j].y, acc[i][j]);
          acc[i][j] = fmaf(av[i].z, wb[j].x, acc[i][j]);
          acc[i][j] = fmaf(av[i].w, wb[j].y, acc[i][j]);
        }
    }
  }
  float fcnt[4], inv[4], dx[4], dy[4], dz[4];
  #pragma unroll
  for (int i = 0; i < 4; ++i) {
    int q = q0 + q0l + i;
    if (q < M_) {
      float4 ps = possum4[q];
      float fc = ps.w;
      fcnt[i] = fc;
      inv[i] = 1.f / fmaxf(fc, 1.f);
      dx[i] = ps.x - fc * qxyz[q * 4 + 1];
      dy[i] = ps.y - fc * qxyz[q * 4 + 2];
      dz[i] = ps.z - fc * qxyz[q * 4 + 3];
    } else {
      fcnt[i] = 0.f; inv[i] = 1.f; dx[i] = dy[i] = dz[i] = 0.f;
    }
  }
  float psum[4], psq[4];
  #pragma unroll
  for (int j = 0; j < 4; ++j) {
    int c = cb + 32 * j;
    float w0 = Wp[c * 3 + 0], w1 = Wp[c * 3 + 1], w2 = Wp[c * 3 + 2];
    float bb = bm[c] + bp[c];
    float s = 0.f, s2 = 0.f;
    #pragma unroll
    for (int i = 0; i < 4; ++i) {
      int q = q0 + q0l + i;
      float v = acc[i][j] + dx[i] * w0 + dy[i] * w1 + dz[i] * w2 + fcnt[i] * bb;
      float val = v * inv[i];
      if (q >= M_) val = 0.f;       // padded rows contribute zero
      if (q < M_) out[q * 128 + c] = val;
      s += val; s2 += val * val;
    }
    psum[j] = s; psq[j] = s2;
  }
  __syncthreads();                  // all sA reads done -> reuse as red
  float* red = sA;                  // [0..1023]=sum, [1024..2047]=sumsq
  int rg = t >> 5;
  #pragma unroll
  for (int j = 0; j < 4; ++j) {
    int c = cb + 32 * j;
    red[c * 8 + rg] = psum[j];
    red[1024 + c * 8 + rg] = psq[j];
  }
  __syncthreads();
  if (t < 128) {
    float s = 0.f, s2 = 0.f;
    #pragma unroll
    for (int r = 0; r < 8; ++r) {
      s += red[t * 8 + r];
      s2 += red[1024 + t * 8 + r];
    }
    atomicAdd(&stats[t], s);
    atomicAdd(&stats[128 + t], s2);
  }
}

// inline BN-prep (redundant per block, 128 rsqrt) + normalize + ReLU
__global__ __launch_bounds__(256) void k_bnapply(float* __restrict__ out,
                                                 const float* __restrict__ stats,
                                                 const float* __restrict__ gamma,
                                                 const float* __restrict__ beta,
                                                 float inv_m, int total4) {
  __shared__ float sc[128], sh[128];
  int t = threadIdx.x;
  if (t < 128) {
    float mu = stats[t] * inv_m;
    float var = stats[128 + t] * inv_m - mu * mu;
    var = fmaxf(var, 0.f);
    float s = gamma[t] * rsqrtf(var + 1e-5f);
    sc[t] = s;
    sh[t] = beta[t] - mu * s;
  }
  __syncthreads();
  const float4* sc4 = (const float4*)sc;
  const float4* sh4 = (const float4*)sh;
  float4* o4 = (float4*)out;
  for (int i = blockIdx.x * blockDim.x + t; i < total4;
       i += gridDim.x * blockDim.x) {
    float4 v = o4[i];
    float4 s = sc4[i & 31];
    float4 h = sh4[i & 31];
    v.x = fmaxf(fmaf(v.x, s.x, h.x), 0.f);
    v.y = fmaxf(fmaf(v.y, s.y, h.y), 0.f);
    v.z = fmaxf(fmaf(v.z, s.z, h.z), 0.f);
    v.w = fmaxf(fmaf(v.w, s.w, h.w), 0.f);
    o4[i] = v;
  }
}

static inline size_t align256(size_t x) { return (x + 255) & ~(size_t)255; }

extern "C" void kernel_launch(void* const* d_in, const int* in_sizes, int n_in,
                              void* d_out, int out_size, void* d_ws, size_t ws_size,
                              hipStream_t stream) {
  const float* ref_bxyz   = (const float*)d_in[0];
  const float* ref_feat   = (const float*)d_in[1];
  const float* query_bxyz = (const float*)d_in[2];
  const int*   e_ref      = (const int*)d_in[3];
  const int*   e_query    = (const int*)d_in[4];
  const float* W_pos      = (const float*)d_in[5];
  const float* b_pos      = (const float*)d_in[6];
  const float* W_mlp      = (const float*)d_in[7];
  const float* b_mlp      = (const float*)d_in[8];
  const float* gamma      = (const float*)d_in[9];
  const float* beta       = (const float*)d_in[10];

  int N_ = in_sizes[0] / 4;
  int M_ = in_sizes[2] / 4;
  int E_ = in_sizes[3];

  char* ws = (char*)d_ws;
  size_t off = 0;
  int*   head4  = (int*)(ws + off);   off += align256((size_t)M_ * 4 * 4);
  int2*  node   = (int2*)(ws + off);  off += align256((size_t)E_ * 8);
  float* stats  = (float*)(ws + off); off += align256(2 * 128 * 4);
  float* possum = (float*)(ws + off); off += align256((size_t)M_ * 4 * 4);
  float* accF   = (float*)(ws + off); off += align256((size_t)M_ * 128 * 4);
  uint4* featb  = (uint4*)(ws + off);

  hipMemsetAsync(head4, 0xFF, (size_t)M_ * 4 * 4, stream);   // all chains empty

  float* out = (float*)d_out;
  int n8 = N_ * 16;                 // uint4 groups (8 floats each)
  int nwork = (E_ > n8) ? E_ : n8;

  k_build_cvt<<<(nwork + 255) / 256, 256, 0, stream>>>(
      e_query, e_ref, head4, node, (const float4*)ref_feat, featb, stats, E_, n8);
  k_accum_b<<<(M_ + 15) / 16, 256, 0, stream>>>(head4, node, featb, ref_bxyz,
                                                (float4*)accF, possum, M_);
  k_gemm<<<(M_ + 31) / 32, 256, 0, stream>>>(accF, (const float4*)possum,
                                             query_bxyz, W_mlp, W_pos, b_mlp,
                                             b_pos, out, stats, M_);
  k_bnapply<<<1024, 256, 0, stream>>>(out, stats, gamma, beta, 1.f / (float)M_,
                                      M_ * 32);
}